// Round 3
// baseline (747.648 us; speedup 1.0000x reference)
//
#include <hip/hip_runtime.h>
#include <stdint.h>

#define T_TOK 16384
#define DIM 512
#define HID 2048
#define NE 16
#define TOPK 4
#define BM 256
#define BN 256
#define BKT 64
#define PAIR_CAP 69632      // 65536 + 16*256 padding
#define MAX_TILES 272       // PAIR_CAP / BM
#define NB_CNT 64

typedef short s8v __attribute__((ext_vector_type(8)));
typedef float f4v __attribute__((ext_vector_type(4)));
typedef unsigned int u4v __attribute__((ext_vector_type(4)));

__device__ __forceinline__ unsigned short f2bf(float f) {
  unsigned int u = __builtin_bit_cast(unsigned int, f);
  u = (u + 0x7fffu + ((u >> 16) & 1u)) >> 16;
  return (unsigned short)u;
}
__device__ __forceinline__ float bf2f(unsigned short h) {
  return __builtin_bit_cast(float, (unsigned int)h << 16);
}

// async global->LDS, 16B per lane. LDS dest is wave-uniform base + lane*16.
__device__ __forceinline__ void gload16(const void* g, void* l) {
  __builtin_amdgcn_global_load_lds(
      (const __attribute__((address_space(1))) unsigned int*)(uintptr_t)g,
      (__attribute__((address_space(3))) unsigned int*)(uintptr_t)l,
      16, 0, 0);
}

// src [z][R][C] fp32 -> dst [z][C][R] bf16
__global__ __launch_bounds__(256) void k_transpose_cast(const float* __restrict__ src,
                                                        unsigned short* __restrict__ dst,
                                                        int R, int C) {
  __shared__ float tile[32][33];
  size_t zo = (size_t)blockIdx.z * R * C;
  src += zo; dst += zo;
  int c0 = blockIdx.x * 32, r0 = blockIdx.y * 32;
  int tx = threadIdx.x, ty = threadIdx.y;
#pragma unroll
  for (int i = 0; i < 4; ++i)
    tile[ty + 8 * i][tx] = src[(size_t)(r0 + ty + 8 * i) * C + c0 + tx];
  __syncthreads();
#pragma unroll
  for (int i = 0; i < 4; ++i)
    dst[(size_t)(c0 + ty + 8 * i) * R + r0 + tx] = f2bf(tile[tx][ty + 8 * i]);
}

// ---------------- routing (+ fused x->bf16 cast) ----------------
__global__ __launch_bounds__(256) void k_router(const float* __restrict__ x,
                                                const float* __restrict__ rw,
                                                const float* __restrict__ rb,
                                                int* __restrict__ topki,
                                                float* __restrict__ topkg,
                                                unsigned short* __restrict__ xb) {
  int wv = threadIdx.x >> 6, lane = threadIdx.x & 63;
  int t = blockIdx.x * 4 + wv;
  const float* xr = x + (size_t)t * DIM;
  unsigned short* xbr = xb + (size_t)t * DIM;
  double acc[NE];
#pragma unroll
  for (int e = 0; e < NE; ++e) acc[e] = 0.0;
  for (int it = 0; it < DIM / 64; ++it) {
    float xv = xr[it * 64 + lane];
    xbr[it * 64 + lane] = f2bf(xv);
    const float* r = rw + (size_t)(it * 64 + lane) * NE;
#pragma unroll
    for (int e = 0; e < NE; ++e) acc[e] += (double)xv * (double)r[e];
  }
#pragma unroll
  for (int off = 32; off >= 1; off >>= 1) {
#pragma unroll
    for (int e = 0; e < NE; ++e) acc[e] += __shfl_xor(acc[e], off, 64);
  }
  if (lane == 0) {
    float v[NE];
#pragma unroll
    for (int e = 0; e < NE; ++e) v[e] = (float)acc[e] + rb[e];
    int idx[TOPK]; float val[TOPK];
#pragma unroll
    for (int k = 0; k < TOPK; ++k) {
      float best = -1e30f; int bi = 0;
#pragma unroll
      for (int e = 0; e < NE; ++e)
        if (v[e] > best) { best = v[e]; bi = e; }
      idx[k] = bi; val[k] = best; v[bi] = -1e30f;
    }
    float m = val[0], s = 0.f, g[TOPK];
#pragma unroll
    for (int k = 0; k < TOPK; ++k) { g[k] = __expf(val[k] - m); s += g[k]; }
    float inv = 1.f / s;
#pragma unroll
    for (int k = 0; k < TOPK; ++k) {
      topki[t * TOPK + k] = idx[k];
      topkg[t * TOPK + k] = g[k] * inv;
    }
  }
}

// meta layout (ints): [0]=tiles_total, [1..17]=padded offsets po[0..16],
// [32..1055]=blockbase[64][16], [1056..2079]=hist[64][16]
__global__ __launch_bounds__(256) void k_count(const int* __restrict__ topki,
                                               int* __restrict__ meta) {
  __shared__ int lcnt[NE];
  int tid = threadIdx.x;
  if (tid < NE) lcnt[tid] = 0;
  __syncthreads();
  int base = blockIdx.x * 1024 + tid * 4;
#pragma unroll
  for (int j = 0; j < 4; ++j) atomicAdd(&lcnt[topki[base + j]], 1);
  __syncthreads();
  if (tid < NE) meta[1056 + blockIdx.x * NE + tid] = lcnt[tid];
}

__global__ __launch_bounds__(256) void k_plan(int* __restrict__ meta,
                                              int* __restrict__ ptok,
                                              float* __restrict__ pgate) {
  __shared__ int cnt_s[NE], po_s[NE + 1];
  int tid = threadIdx.x;
  if (tid < NE) {
    int s = 0;
    for (int b = 0; b < NB_CNT; ++b) s += meta[1056 + b * NE + tid];
    cnt_s[tid] = s;
  }
  __syncthreads();
  if (tid == 0) {
    int off = 0;
    for (int e = 0; e < NE; ++e) {
      po_s[e] = off;
      meta[1 + e] = off;
      off += ((cnt_s[e] + BM - 1) / BM) * BM;
    }
    po_s[NE] = off;
    meta[1 + NE] = off;
    meta[0] = off / BM;
  }
  __syncthreads();
  if (tid < NE) {
    int run = po_s[tid];
    for (int b = 0; b < NB_CNT; ++b) {
      meta[32 + b * NE + tid] = run;
      run += meta[1056 + b * NE + tid];
    }
  }
  for (int e = 0; e < NE; ++e) {
    int start = po_s[e] + cnt_s[e], end = po_s[e + 1];
    for (int i = start + tid; i < end; i += 256) { ptok[i] = 0; pgate[i] = 0.f; }
  }
}

__global__ __launch_bounds__(256) void k_scatter(const int* __restrict__ topki,
                                                 const float* __restrict__ topkg,
                                                 const int* __restrict__ meta,
                                                 int* __restrict__ ptok,
                                                 float* __restrict__ pgate,
                                                 int* __restrict__ sinv) {
  __shared__ int lcnt[NE];
  int tid = threadIdx.x;
  if (tid < NE) lcnt[tid] = 0;
  __syncthreads();
  int base = blockIdx.x * 1024 + tid * 4;
#pragma unroll
  for (int j = 0; j < 4; ++j) {
    int i = base + j;
    int e = topki[i];
    int r = atomicAdd(&lcnt[e], 1);
    int slot = meta[32 + blockIdx.x * NE + e] + r;
    ptok[slot] = i >> 2;
    pgate[slot] = topkg[i];
    sinv[i] = slot;
  }
}

// ---------------- 256x256 8-phase pipelined GEMM dispatch ----------------
// blockIdx.x < 2 : gemm2 role (long K first), chunk c2 <- hsrc
// blockIdx.x >= 2: gemm1 role, chunk c1 -> hdst
// LDS: 2 buffers x (A 256x64 + B 256x64) bf16, XOR-swizzled (16B group ^ (row&7)).
// Regions per buffer: A1=rows 0-127, A2=128-255; B1, B2 likewise.
// Phase (mq,nq) computes C-quadrant rows mq*128, cols nq*128 and reads ONLY A(mq),B(nq).
// Quadrant order per K-tile: (0,0),(0,1),(1,0),(1,1).
// Stage slots (1 half-tile = 2 gload16/thread per phase), iter j = tiles 2j(buf0),2j+1(buf1):
//   p0:A2(2j+1)->buf1  p1:B2(2j+1)->buf1  p2:A1(2j+2)->buf0  p3:B1(2j+2)->buf0
//   p4:A2(2j+2)->buf0  p5:B2(2j+2)->buf0  p6:A1(2j+3)->buf1  p7:B1(2j+3)->buf1
// Guards (before end barrier): p0:vmcnt(6)  p3:vmcnt(8)  p4:vmcnt(6)  p7:vmcnt(8).

#define MBAR() asm volatile("s_barrier" ::: "memory")
#define EBAR() asm volatile("s_barrier" ::: "memory")
#define SP1() __builtin_amdgcn_s_setprio(1)
#define SP0() __builtin_amdgcn_s_setprio(0)
#define LGK0() do { asm volatile("s_waitcnt lgkmcnt(0)" ::: "memory"); \
                    __builtin_amdgcn_sched_barrier(0); } while (0)
#define VMC(n) asm volatile("s_waitcnt vmcnt(" #n ")" ::: "memory")
#define NOP ((void)0)

// stage half-tile: rg 0=A1,1=A2,2=B1,3=B2 of K-tile kt into buffer c
#define STG(rg, kt, c) do {                                                            \
    int _k = (kt) * BKT;                                                               \
    if ((rg) < 2) {                                                                    \
      gload16(aP[rg][0] + _k, (char*)&Al[c][0] + (rg) * 16384 + w * 1024);             \
      gload16(aP[rg][1] + _k, (char*)&Al[c][0] + (rg) * 16384 + 8192 + w * 1024);      \
    } else {                                                                           \
      gload16(bP[(rg) - 2][0] + _k, (char*)&Bl[c][0] + ((rg) - 2) * 16384 + w * 1024); \
      gload16(bP[(rg) - 2][1] + _k, (char*)&Bl[c][0] + ((rg) - 2) * 16384 + 8192 + w * 1024); \
    }                                                                                  \
  } while (0)

#define RDA(c, mq) do {                                                                \
    _Pragma("unroll")                                                                  \
    for (int mt = 0; mt < 4; ++mt) {                                                   \
      af[mt][0] = __builtin_bit_cast(s8v, *(const u4v*)&Al[c][(mq) * 8192 + aoff + mt * 1024 + cs0]); \
      af[mt][1] = __builtin_bit_cast(s8v, *(const u4v*)&Al[c][(mq) * 8192 + aoff + mt * 1024 + cs1]); \
    }                                                                                  \
  } while (0)

#define RDB(c, nq) do {                                                                \
    _Pragma("unroll")                                                                  \
    for (int nt = 0; nt < 2; ++nt) {                                                   \
      bfr[nt][0] = __builtin_bit_cast(s8v, *(const u4v*)&Bl[c][(nq) * 8192 + boff + nt * 1024 + cs0]); \
      bfr[nt][1] = __builtin_bit_cast(s8v, *(const u4v*)&Bl[c][(nq) * 8192 + boff + nt * 1024 + cs1]); \
    }                                                                                  \
  } while (0)

#define MMQ(mq, nq) do {                                                               \
    _Pragma("unroll")                                                                  \
    for (int mt = 0; mt < 4; ++mt) {                                                   \
      _Pragma("unroll")                                                                \
      for (int nt = 0; nt < 2; ++nt) {                                                 \
        acc[(mq) * 4 + mt][(nq) * 2 + nt] = __builtin_amdgcn_mfma_f32_16x16x32_bf16(   \
            af[mt][0], bfr[nt][0], acc[(mq) * 4 + mt][(nq) * 2 + nt], 0, 0, 0);        \
        acc[(mq) * 4 + mt][(nq) * 2 + nt] = __builtin_amdgcn_mfma_f32_16x16x32_bf16(   \
            af[mt][1], bfr[nt][1], acc[(mq) * 4 + mt][(nq) * 2 + nt], 0, 0, 0);        \
      }                                                                                \
    }                                                                                  \
  } while (0)

// phase: [RDA] RDB STAGE | bar | lgkmcnt(0) MFMA | WAIT | bar
#define PH(c, mq, nq, doA, STAGE, WAITC) do {  \
    if (doA) RDA(c, mq);                       \
    RDB(c, nq);                                \
    STAGE;                                     \
    MBAR();                                    \
    LGK0();                                    \
    SP1(); MMQ(mq, nq); SP0();                 \
    WAITC;                                     \
    EBAR();                                    \
  } while (0)

__global__ __launch_bounds__(512, 2) void k_pipe(const unsigned short* __restrict__ xb,
                                                 const unsigned short* __restrict__ w1t,
                                                 const float* __restrict__ b1,
                                                 const unsigned short* __restrict__ w2t,
                                                 const float* __restrict__ b2,
                                                 const int* __restrict__ ptok,
                                                 const float* __restrict__ pgate,
                                                 const int* __restrict__ meta,
                                                 unsigned short* __restrict__ hdst,
                                                 const unsigned short* __restrict__ hsrc,
                                                 unsigned short* __restrict__ yslot,
                                                 float* __restrict__ out,
                                                 int c1, int c2, int C) {
  __shared__ __align__(16) unsigned short Al[2][BM * BKT];   // 2 x 32 KB
  __shared__ __align__(16) unsigned short Bl[2][BN * BKT];   // 2 x 32 KB
  int tid = threadIdx.x;
  int lane = tid & 63, w = tid >> 6;       // 8 waves
  int wm = w >> 2, wn = w & 3;             // 2 x 4 wave grid within a quadrant
  int lrow = lane & 15, quad = lane >> 4;
  int r7 = lrow & 7;
  int sub = lane >> 3, lg = (lane & 7) ^ sub;

  bool g2 = blockIdx.x < 2;
  int chunk = g2 ? c2 : c1;
  if (chunk < 0) return;
  int tile = chunk * C + blockIdx.y;
  if (tile >= meta[0]) return;
  int row0 = tile * BM;
  int e = 0;
#pragma unroll
  for (int i = 1; i < NE; ++i)
    if (row0 >= meta[1 + i]) e = i;
  int nblock = g2 ? (int)blockIdx.x * BN : ((int)blockIdx.x - 2) * BN;

  const unsigned short* aP[2][2];
  const unsigned short* bP[2][2];
  int NKT;
  if (!g2) {
    NKT = DIM / BKT;   // 8
#pragma unroll
    for (int h = 0; h < 2; ++h)
#pragma unroll
      for (int t = 0; t < 2; ++t) {
        int r = h * 128 + t * 64 + w * 8 + sub;
        aP[h][t] = xb + (size_t)ptok[row0 + r] * DIM + lg * 8;
        bP[h][t] = w1t + ((size_t)e * HID + nblock + r) * DIM + lg * 8;
      }
  } else {
    NKT = HID / BKT;   // 32
#pragma unroll
    for (int h = 0; h < 2; ++h)
#pragma unroll
      for (int t = 0; t < 2; ++t) {
        int r = h * 128 + t * 64 + w * 8 + sub;
        aP[h][t] = hsrc + ((size_t)blockIdx.y * BM + r) * HID + lg * 8;
        bP[h][t] = w2t + ((size_t)e * DIM + nblock + r) * HID + lg * 8;
      }
  }

  int aoff = (wm * 64 + lrow) * BKT;   // row base within a 128-row A region
  int boff = (wn * 32 + lrow) * BKT;   // row base within a 128-row B region
  int cs0 = (quad ^ r7) * 8;
  int cs1 = ((4 + quad) ^ r7) * 8;

  f4v acc[8][4] = {};
  s8v af[4][2];
  s8v bfr[2][2];

  // prologue: A1(0) B1(0) A2(0) B2(0) A1(1) B1(1); need oldest 2 landed
  STG(0, 0, 0); STG(2, 0, 0); STG(1, 0, 0); STG(3, 0, 0);
  STG(0, 1, 1); STG(2, 1, 1);
  VMC(8);
  EBAR();

  int NI = NKT >> 1;
  for (int i = 0; i < NI - 1; ++i) {
    int bt = 2 * i;
    PH(0, 0, 0, true,  STG(1, bt + 1, 1), VMC(6));   // p0: A2(bt+1)->buf1
    PH(0, 0, 1, false, STG(3, bt + 1, 1), NOP);      // p1: B2(bt+1)->buf1
    PH(0, 1, 0, true,  STG(0, bt + 2, 0), NOP);      // p2: A1(bt+2)->buf0
    PH(0, 1, 1, false, STG(2, bt + 2, 0), VMC(8));   // p3: B1(bt+2)->buf0
    PH(1, 0, 0, true,  STG(1, bt + 2, 0), VMC(6));   // p4: A2(bt+2)->buf0
    PH(1, 0, 1, false, STG(3, bt + 2, 0), NOP);      // p5: B2(bt+2)->buf0
    PH(1, 1, 0, true,  STG(0, bt + 3, 1), NOP);      // p6: A1(bt+3)->buf1
    PH(1, 1, 1, false, STG(2, bt + 3, 1), VMC(8));   // p7: B1(bt+3)->buf1
  }
  {  // tail iteration: tiles NKT-2 (buf0), NKT-1 (buf1); drain
    int bt = NKT - 2;
    PH(0, 0, 0, true,  STG(1, bt + 1, 1), VMC(6));
    PH(0, 0, 1, false, STG(3, bt + 1, 1), NOP);
    PH(0, 1, 0, true,  NOP, NOP);
    PH(0, 1, 1, false, NOP, VMC(4));
    PH(1, 0, 0, true,  NOP, VMC(0));
    PH(1, 0, 1, false, NOP, NOP);
    PH(1, 1, 0, true,  NOP, NOP);
    PH(1, 1, 1, false, NOP, NOP);
  }

  if (!g2) {
    // ======== GEMM1 epilogue: hdst = relu(acc + b1) ========
    size_t hrow0 = (size_t)blockIdx.y * BM;
#pragma unroll
    for (int nq = 0; nq < 2; ++nq) {
#pragma unroll
      for (int nt = 0; nt < 2; ++nt) {
        int gcol = nblock + nq * 128 + wn * 32 + nt * 16 + lrow;
        float bias = b1[e * HID + gcol];
#pragma unroll
        for (int mq = 0; mq < 2; ++mq) {
#pragma unroll
          for (int mt = 0; mt < 4; ++mt) {
#pragma unroll
            for (int j = 0; j < 4; ++j) {
              int grow = mq * 128 + wm * 64 + mt * 16 + quad * 4 + j;
              float v = acc[mq * 4 + mt][nq * 2 + nt][j] + bias;
              hdst[(hrow0 + grow) * HID + gcol] = f2bf(v > 0.f ? v : 0.f);
            }
          }
        }
      }
    }
  } else {
    // ======== GEMM2 epilogue: y[slot] = gate*(acc + b2) ========
    float bias[2][2];
#pragma unroll
    for (int nq = 0; nq < 2; ++nq)
#pragma unroll
      for (int nt = 0; nt < 2; ++nt)
        bias[nq][nt] = b2[e * DIM + nblock + nq * 128 + wn * 32 + nt * 16 + lrow];
    if (yslot) {
#pragma unroll
      for (int mq = 0; mq < 2; ++mq) {
#pragma unroll
        for (int mt = 0; mt < 4; ++mt) {
#pragma unroll
          for (int j = 0; j < 4; ++j) {
            int p = row0 + mq * 128 + wm * 64 + mt * 16 + quad * 4 + j;
            float g = pgate[p];
            unsigned short* yr = yslot + (size_t)p * DIM + nblock + wn * 32 + lrow;
#pragma unroll
            for (int nq = 0; nq < 2; ++nq)
#pragma unroll
              for (int nt = 0; nt < 2; ++nt)
                yr[nq * 128 + nt * 16] = f2bf(g * (acc[mq * 4 + mt][nq * 2 + nt][j] + bias[nq][nt]));
          }
        }
      }
    } else {
#pragma unroll
      for (int mq = 0; mq < 2; ++mq) {
#pragma unroll
        for (int mt = 0; mt < 4; ++mt) {
#pragma unroll
          for (int j = 0; j < 4; ++j) {
            int p = row0 + mq * 128 + wm * 64 + mt * 16 + quad * 4 + j;
            float g = pgate[p];
            if (g != 0.f) {
              int tok = ptok[p];
              float* orow = out + (size_t)tok * DIM + nblock + wn * 32 + lrow;
#pragma unroll
              for (int nq = 0; nq < 2; ++nq)
#pragma unroll
                for (int nt = 0; nt < 2; ++nt)
                  atomicAdd(orow + nq * 128 + nt * 16, g * (acc[mq * 4 + mt][nq * 2 + nt][j] + bias[nq][nt]));
            }
          }
        }
      }
    }
  }
}

// out[t][d] = sum_k yslot[sinv[t*4+k]][d]   (yslot is bf16)
__global__ __launch_bounds__(256) void k_gather(const unsigned short* __restrict__ yslot,
                                                const int* __restrict__ sinv,
                                                float* __restrict__ out) {
  int id = blockIdx.x * 256 + threadIdx.x;
  int t = id >> 7, d4 = (id & 127) << 2;
  int4 s = *(const int4*)(sinv + t * 4);
  int sl[4] = {s.x, s.y, s.z, s.w};
  float sum0 = 0.f, sum1 = 0.f, sum2 = 0.f, sum3 = 0.f;
#pragma unroll
  for (int k = 0; k < 4; ++k) {
    ushort4 v = *(const ushort4*)(yslot + (size_t)sl[k] * DIM + d4);
    sum0 += bf2f(v.x); sum1 += bf2f(v.y); sum2 += bf2f(v.z); sum3 += bf2f(v.w);
  }
  float4 r; r.x = sum0; r.y = sum1; r.z = sum2; r.w = sum3;
  *(float4*)(out + (size_t)t * DIM + d4) = r;
}

extern "C" void kernel_launch(void* const* d_in, const int* in_sizes, int n_in,
                              void* d_out, int out_size, void* d_ws, size_t ws_size,
                              hipStream_t stream) {
  const float* x  = (const float*)d_in[0];
  const float* rw = (const float*)d_in[1];
  const float* rb = (const float*)d_in[2];
  const float* w1 = (const float*)d_in[3];
  const float* b1 = (const float*)d_in[4];
  const float* w2 = (const float*)d_in[5];
  const float* b2 = (const float*)d_in[6];
  float* out = (float*)d_out;
  char* ws = (char*)d_ws;

  size_t o_xb    = 0;
  size_t o_w1t   = o_xb    + (size_t)T_TOK * DIM * 2;
  size_t o_w2t   = o_w1t   + (size_t)NE * DIM * HID * 2;
  size_t o_topki = o_w2t   + (size_t)NE * DIM * HID * 2;
  size_t o_topkg = o_topki + (size_t)T_TOK * TOPK * 4;
  size_t o_meta  = o_topkg + (size_t)T_TOK * TOPK * 4;
  size_t o_ptok  = o_meta  + 16384;
  size_t o_pgate = o_ptok  + (size_t)PAIR_CAP * 4;
  size_t o_sinv  = o_pgate + (size_t)PAIR_CAP * 4;
  size_t o_yslot = o_sinv  + (size_t)T_TOK * TOPK * 4;
  size_t o_hb    = o_yslot + (size_t)PAIR_CAP * DIM * 2;   // bf16 yslot

  unsigned short* xb   = (unsigned short*)(ws + o_xb);
  unsigned short* w1t  = (unsigned short*)(ws + o_w1t);
  unsigned short* w2t  = (unsigned short*)(ws + o_w2t);
  int*            tki  = (int*)(ws + o_topki);
  float*          tkg  = (float*)(ws + o_topkg);
  int*            meta = (int*)(ws + o_meta);
  int*            ptok = (int*)(ws + o_ptok);
  float*          pgt  = (float*)(ws + o_pgate);
  int*            sinv = (int*)(ws + o_sinv);

  size_t tile_h = (size_t)BM * HID * 2;   // 1 MB per 256-row tile
  size_t avail = ws_size > o_hb ? ws_size - o_hb : 0;
  long Cd = (long)(avail / (2 * tile_h));
  int use_slot = Cd >= 1;

  k_router<<<T_TOK / 4, 256, 0, stream>>>(x, rw, rb, tki, tkg, xb);
  k_transpose_cast<<<dim3(HID / 32, DIM / 32, NE), dim3(32, 8), 0, stream>>>(w1, w1t, DIM, HID);
  k_transpose_cast<<<dim3(DIM / 32, HID / 32, NE), dim3(32, 8), 0, stream>>>(w2, w2t, HID, DIM);
  k_count<<<NB_CNT, 256, 0, stream>>>(tki, meta);
  k_plan<<<1, 256, 0, stream>>>(meta, ptok, pgt);
  k_scatter<<<NB_CNT, 256, 0, stream>>>(tki, tkg, meta, ptok, pgt, sinv);

  if (use_slot) {
    unsigned short* ysl = (unsigned short*)(ws + o_yslot);
    int C = (int)(Cd > MAX_TILES ? MAX_TILES : Cd);
    int n_chunks = (MAX_TILES + C - 1) / C;
    unsigned short* hb0 = (unsigned short*)(ws + o_hb);
    unsigned short* hb1 = hb0 + (size_t)C * BM * HID;
    for (int i = 0; i <= n_chunks; ++i) {
      unsigned short* dst = (i & 1) ? hb1 : hb0;
      unsigned short* src = (i & 1) ? hb0 : hb1;
      int c1 = (i < n_chunks) ? i : -1;
      int c2 = i - 1;
      k_pipe<<<dim3(10, C), 512, 0, stream>>>(xb, w1t, b1, w2t, b2, ptok, pgt, meta,
                                              dst, src, ysl, out, c1, c2, C);
    }
    k_gather<<<T_TOK * DIM / 4 / 256, 256, 0, stream>>>(ysl, sinv, out);
  } else {
    // fallback: single hbuf at o_yslot, serial role launches, atomic epilogue
    long Cf = (long)((ws_size - o_yslot) / tile_h);
    int C = (int)(Cf < 1 ? 1 : (Cf > MAX_TILES ? MAX_TILES : Cf));
    int n_chunks = (MAX_TILES + C - 1) / C;
    unsigned short* hb = (unsigned short*)(ws + o_yslot);
    hipMemsetAsync(d_out, 0, (size_t)T_TOK * DIM * 4, stream);
    for (int i = 0; i < n_chunks; ++i) {
      k_pipe<<<dim3(10, C), 512, 0, stream>>>(xb, w1t, b1, w2t, b2, ptok, pgt, meta,
                                              hb, hb, nullptr, out, i, -1, C);
      k_pipe<<<dim3(10, C), 512, 0, stream>>>(xb, w1t, b1, w2t, b2, ptok, pgt, meta,
                                              hb, hb, nullptr, out, -1, i, C);
    }
  }
}

// Round 4
// 676.318 us; speedup vs baseline: 1.1055x; 1.1055x over previous
//
#include <hip/hip_runtime.h>
#include <stdint.h>

#define T_TOK 16384
#define DIM 512
#define HID 2048
#define NE 16
#define TOPK 4
#define BM 256
#define BN 256
#define BKT 64
#define PAIR_CAP 69632      // 65536 + 16*256 padding
#define MAX_TILES 272       // PAIR_CAP / BM
#define NB_CNT 64
#define QOFF 2080           // meta[] index of per-launch queue counters

typedef short s8v __attribute__((ext_vector_type(8)));
typedef float f4v __attribute__((ext_vector_type(4)));
typedef unsigned int u4v __attribute__((ext_vector_type(4)));

__device__ __forceinline__ unsigned short f2bf(float f) {
  unsigned int u = __builtin_bit_cast(unsigned int, f);
  u = (u + 0x7fffu + ((u >> 16) & 1u)) >> 16;
  return (unsigned short)u;
}
__device__ __forceinline__ float bf2f(unsigned short h) {
  return __builtin_bit_cast(float, (unsigned int)h << 16);
}

// async global->LDS, 16B per lane. LDS dest is wave-uniform base + lane*16.
__device__ __forceinline__ void gload16(const void* g, void* l) {
  __builtin_amdgcn_global_load_lds(
      (const __attribute__((address_space(1))) unsigned int*)(uintptr_t)g,
      (__attribute__((address_space(3))) unsigned int*)(uintptr_t)l,
      16, 0, 0);
}

// src [z][R][C] fp32 -> dst [z][C][R] bf16
__global__ __launch_bounds__(256) void k_transpose_cast(const float* __restrict__ src,
                                                        unsigned short* __restrict__ dst,
                                                        int R, int C) {
  __shared__ float tile[32][33];
  size_t zo = (size_t)blockIdx.z * R * C;
  src += zo; dst += zo;
  int c0 = blockIdx.x * 32, r0 = blockIdx.y * 32;
  int tx = threadIdx.x, ty = threadIdx.y;
#pragma unroll
  for (int i = 0; i < 4; ++i)
    tile[ty + 8 * i][tx] = src[(size_t)(r0 + ty + 8 * i) * C + c0 + tx];
  __syncthreads();
#pragma unroll
  for (int i = 0; i < 4; ++i)
    dst[(size_t)(c0 + ty + 8 * i) * R + r0 + tx] = f2bf(tile[tx][ty + 8 * i]);
}

// ---------------- routing (+ fused x->bf16 cast) ----------------
__global__ __launch_bounds__(256) void k_router(const float* __restrict__ x,
                                                const float* __restrict__ rw,
                                                const float* __restrict__ rb,
                                                int* __restrict__ topki,
                                                float* __restrict__ topkg,
                                                unsigned short* __restrict__ xb) {
  int wv = threadIdx.x >> 6, lane = threadIdx.x & 63;
  int t = blockIdx.x * 4 + wv;
  const float* xr = x + (size_t)t * DIM;
  unsigned short* xbr = xb + (size_t)t * DIM;
  double acc[NE];
#pragma unroll
  for (int e = 0; e < NE; ++e) acc[e] = 0.0;
  for (int it = 0; it < DIM / 64; ++it) {
    float xv = xr[it * 64 + lane];
    xbr[it * 64 + lane] = f2bf(xv);
    const float* r = rw + (size_t)(it * 64 + lane) * NE;
#pragma unroll
    for (int e = 0; e < NE; ++e) acc[e] += (double)xv * (double)r[e];
  }
#pragma unroll
  for (int off = 32; off >= 1; off >>= 1) {
#pragma unroll
    for (int e = 0; e < NE; ++e) acc[e] += __shfl_xor(acc[e], off, 64);
  }
  if (lane == 0) {
    float v[NE];
#pragma unroll
    for (int e = 0; e < NE; ++e) v[e] = (float)acc[e] + rb[e];
    int idx[TOPK]; float val[TOPK];
#pragma unroll
    for (int k = 0; k < TOPK; ++k) {
      float best = -1e30f; int bi = 0;
#pragma unroll
      for (int e = 0; e < NE; ++e)
        if (v[e] > best) { best = v[e]; bi = e; }
      idx[k] = bi; val[k] = best; v[bi] = -1e30f;
    }
    float m = val[0], s = 0.f, g[TOPK];
#pragma unroll
    for (int k = 0; k < TOPK; ++k) { g[k] = __expf(val[k] - m); s += g[k]; }
    float inv = 1.f / s;
#pragma unroll
    for (int k = 0; k < TOPK; ++k) {
      topki[t * TOPK + k] = idx[k];
      topkg[t * TOPK + k] = g[k] * inv;
    }
  }
}

// meta layout (ints): [0]=tiles_total, [1..17]=padded offsets po[0..16],
// [32..1055]=blockbase[64][16], [1056..2079]=hist[64][16],
// [2080..3103]=work-queue counters (one per k_pipe launch)
__global__ __launch_bounds__(256) void k_count(const int* __restrict__ topki,
                                               int* __restrict__ meta) {
  __shared__ int lcnt[NE];
  int tid = threadIdx.x;
  if (tid < NE) lcnt[tid] = 0;
  __syncthreads();
  int base = blockIdx.x * 1024 + tid * 4;
#pragma unroll
  for (int j = 0; j < 4; ++j) atomicAdd(&lcnt[topki[base + j]], 1);
  __syncthreads();
  if (tid < NE) meta[1056 + blockIdx.x * NE + tid] = lcnt[tid];
}

__global__ __launch_bounds__(256) void k_plan(int* __restrict__ meta,
                                              int* __restrict__ ptok,
                                              float* __restrict__ pgate) {
  __shared__ int cnt_s[NE], po_s[NE + 1];
  int tid = threadIdx.x;
  for (int i = tid; i < 1024; i += 256) meta[QOFF + i] = 0;
  if (tid < NE) {
    int s = 0;
    for (int b = 0; b < NB_CNT; ++b) s += meta[1056 + b * NE + tid];
    cnt_s[tid] = s;
  }
  __syncthreads();
  if (tid == 0) {
    int off = 0;
    for (int e = 0; e < NE; ++e) {
      po_s[e] = off;
      meta[1 + e] = off;
      off += ((cnt_s[e] + BM - 1) / BM) * BM;
    }
    po_s[NE] = off;
    meta[1 + NE] = off;
    meta[0] = off / BM;
  }
  __syncthreads();
  if (tid < NE) {
    int run = po_s[tid];
    for (int b = 0; b < NB_CNT; ++b) {
      meta[32 + b * NE + tid] = run;
      run += meta[1056 + b * NE + tid];
    }
  }
  for (int e = 0; e < NE; ++e) {
    int start = po_s[e] + cnt_s[e], end = po_s[e + 1];
    for (int i = start + tid; i < end; i += 256) { ptok[i] = 0; pgate[i] = 0.f; }
  }
}

__global__ __launch_bounds__(256) void k_scatter(const int* __restrict__ topki,
                                                 const float* __restrict__ topkg,
                                                 const int* __restrict__ meta,
                                                 int* __restrict__ ptok,
                                                 float* __restrict__ pgate,
                                                 int* __restrict__ sinv) {
  __shared__ int lcnt[NE];
  int tid = threadIdx.x;
  if (tid < NE) lcnt[tid] = 0;
  __syncthreads();
  int base = blockIdx.x * 1024 + tid * 4;
#pragma unroll
  for (int j = 0; j < 4; ++j) {
    int i = base + j;
    int e = topki[i];
    int r = atomicAdd(&lcnt[e], 1);
    int slot = meta[32 + blockIdx.x * NE + e] + r;
    ptok[slot] = i >> 2;
    pgate[slot] = topkg[i];
    sinv[i] = slot;
  }
}

// ---------------- persistent work-queue 256x256 8-phase GEMM ----------------
// Grid = 256 blocks (1/CU, 8 waves). Each block pops items: GEMM2 items first
// (tile of chunk c2, nblock in {0,256}), then GEMM1 items (tile of c1, nblock/256
// in 0..7). 8-phase pipelined K-loop, counted vmcnt(6) at p3/p7 only.
// Phase map per K-tile: (0,0)+{RDA,RDB} (0,1)+{RDB} (1,0)+{RDA} (1,1)+{}.
// Stage slots (steady iter j; bt=2j in buf0, bt+1 in buf1):
//   p0:A2(bt+1)->buf1  p1:A1(bt+2)->buf0  p2:B1(bt+2)->buf0  p3:B2(bt+2)->buf0
//   p4:A2(bt+2)->buf0  p5:A1(bt+3)->buf1  p6:B1(bt+3)->buf1  p7:B2(bt+3)->buf1

#define MBAR() asm volatile("s_barrier" ::: "memory")
#define EBAR() asm volatile("s_barrier" ::: "memory")
#define SP1() __builtin_amdgcn_s_setprio(1)
#define SP0() __builtin_amdgcn_s_setprio(0)
#define LGK0() do { asm volatile("s_waitcnt lgkmcnt(0)" ::: "memory"); \
                    __builtin_amdgcn_sched_barrier(0); } while (0)
#define VMC(n) asm volatile("s_waitcnt vmcnt(" #n ")" ::: "memory")
#define NOP ((void)0)

// stage half-tile region: rg 0=A1,1=A2,2=B1,3=B2 of K-tile kt into buffer c
#define STG(rg, kt, c) do {                                                            \
    int _k = (kt) * BKT;                                                               \
    if ((rg) < 2) {                                                                    \
      gload16(aP[rg][0] + _k, (char*)&Al[c][0] + (rg) * 16384 + w * 1024);             \
      gload16(aP[rg][1] + _k, (char*)&Al[c][0] + (rg) * 16384 + 8192 + w * 1024);      \
    } else {                                                                           \
      gload16(bP[(rg) - 2][0] + _k, (char*)&Bl[c][0] + ((rg) - 2) * 16384 + w * 1024); \
      gload16(bP[(rg) - 2][1] + _k, (char*)&Bl[c][0] + ((rg) - 2) * 16384 + 8192 + w * 1024); \
    }                                                                                  \
  } while (0)

#define RDA(c, mq) do {                                                                \
    _Pragma("unroll")                                                                  \
    for (int mt = 0; mt < 4; ++mt) {                                                   \
      af[mt][0] = __builtin_bit_cast(s8v, *(const u4v*)&Al[c][(mq) * 8192 + aoff + mt * 1024 + cs0]); \
      af[mt][1] = __builtin_bit_cast(s8v, *(const u4v*)&Al[c][(mq) * 8192 + aoff + mt * 1024 + cs1]); \
    }                                                                                  \
  } while (0)

#define RDB(c, nq) do {                                                                \
    _Pragma("unroll")                                                                  \
    for (int nt = 0; nt < 2; ++nt) {                                                   \
      bfr[nq][nt][0] = __builtin_bit_cast(s8v, *(const u4v*)&Bl[c][(nq) * 8192 + boff + nt * 1024 + cs0]); \
      bfr[nq][nt][1] = __builtin_bit_cast(s8v, *(const u4v*)&Bl[c][(nq) * 8192 + boff + nt * 1024 + cs1]); \
    }                                                                                  \
  } while (0)

#define MMQ(mq, nq) do {                                                               \
    _Pragma("unroll")                                                                  \
    for (int mt = 0; mt < 4; ++mt) {                                                   \
      _Pragma("unroll")                                                                \
      for (int nt = 0; nt < 2; ++nt) {                                                 \
        acc[(mq) * 4 + mt][(nq) * 2 + nt] = __builtin_amdgcn_mfma_f32_16x16x32_bf16(   \
            af[mt][0], bfr[nq][nt][0], acc[(mq) * 4 + mt][(nq) * 2 + nt], 0, 0, 0);    \
        acc[(mq) * 4 + mt][(nq) * 2 + nt] = __builtin_amdgcn_mfma_f32_16x16x32_bf16(   \
            af[mt][1], bfr[nq][nt][1], acc[(mq) * 4 + mt][(nq) * 2 + nt], 0, 0, 0);    \
      }                                                                                \
    }                                                                                  \
  } while (0)

#define TAIL(mq, nq) do { MBAR(); LGK0(); SP1(); MMQ(mq, nq); SP0(); } while (0)

__global__ __launch_bounds__(512, 2) void k_pipe(const unsigned short* xb,
                                                 const unsigned short* w1t,
                                                 const float* b1,
                                                 const unsigned short* w2t,
                                                 const float* b2,
                                                 const int* ptok,
                                                 const float* pgate,
                                                 const int* meta,
                                                 int* qctr,
                                                 unsigned short* hdst,
                                                 const unsigned short* hsrc,
                                                 unsigned short* yslot,
                                                 float* out,
                                                 int c1, int c2, int C) {
  __shared__ __align__(16) unsigned short Al[2][BM * BKT];   // 2 x 32 KB
  __shared__ __align__(16) unsigned short Bl[2][BN * BKT];   // 2 x 32 KB
  __shared__ int sh_item;
  int tid = threadIdx.x;
  int lane = tid & 63, w = tid >> 6;       // 8 waves
  int wm = w >> 2, wn = w & 3;             // 2 x 4 wave grid within a quadrant
  int lrow = lane & 15, quad = lane >> 4;
  int r7 = lrow & 7;
  int sub = lane >> 3, lg = (lane & 7) ^ sub;

  int aoff = (wm * 64 + lrow) * BKT;   // row base within a 128-row A region
  int boff = (wn * 32 + lrow) * BKT;   // row base within a 128-row B region
  int cs0 = (quad ^ r7) * 8;
  int cs1 = ((4 + quad) ^ r7) * 8;

  int T = meta[0];
  int t2 = 0, t1 = 0;
  if (c2 >= 0) { t2 = T - c2 * C; t2 = t2 < 0 ? 0 : (t2 > C ? C : t2); }
  if (c1 >= 0) { t1 = T - c1 * C; t1 = t1 < 0 ? 0 : (t1 > C ? C : t1); }
  int n2 = 2 * t2, nit = n2 + 8 * t1;

  for (;;) {
    if (tid == 0) sh_item = atomicAdd(qctr, 1);
    __syncthreads();
    int it = sh_item;
    if (it >= nit) break;

    bool g2 = it < n2;
    int tloc, nb, tile;
    if (g2) { tloc = it >> 1; nb = (it & 1) * BN; tile = c2 * C + tloc; }
    else { int j = it - n2; tloc = j >> 3; nb = (j & 7) * BN; tile = c1 * C + tloc; }
    int row0 = tile * BM;
    int e = 0;
#pragma unroll
    for (int i2 = 1; i2 < NE; ++i2)
      if (row0 >= meta[1 + i2]) e = i2;

    const unsigned short* aP[2][2];
    const unsigned short* bP[2][2];
    int NKT;
    if (!g2) {
      NKT = DIM / BKT;   // 8
#pragma unroll
      for (int h = 0; h < 2; ++h)
#pragma unroll
        for (int t = 0; t < 2; ++t) {
          int r = h * 128 + t * 64 + w * 8 + sub;
          aP[h][t] = xb + (size_t)ptok[row0 + r] * DIM + lg * 8;
          bP[h][t] = w1t + ((size_t)e * HID + nb + r) * DIM + lg * 8;
        }
    } else {
      NKT = HID / BKT;   // 32
#pragma unroll
      for (int h = 0; h < 2; ++h)
#pragma unroll
        for (int t = 0; t < 2; ++t) {
          int r = h * 128 + t * 64 + w * 8 + sub;
          aP[h][t] = hsrc + ((size_t)tloc * BM + r) * HID + lg * 8;
          bP[h][t] = w2t + ((size_t)e * DIM + nb + r) * HID + lg * 8;
        }
    }

    f4v acc[8][4] = {};
    s8v af[4][2];
    s8v bfr[2][2][2];

    // prologue: buf0 <- tile0 (A1,B1,B2,A2); buf1 <- tile1 (A1,B1,B2)
    STG(0, 0, 0); STG(2, 0, 0); STG(3, 0, 0); STG(1, 0, 0);
    STG(0, 1, 1); STG(2, 1, 1); STG(3, 1, 1);
    VMC(4);
    EBAR();

    int NI = NKT >> 1;
    for (int i = 0; i < NI - 1; ++i) {
      int bt = 2 * i;
      // p0
      RDA(0, 0); RDB(0, 0); STG(1, bt + 1, 1);
      TAIL(0, 0); NOP; EBAR();
      // p1
      RDB(0, 1); STG(0, bt + 2, 0);
      TAIL(0, 1); NOP; EBAR();
      // p2
      RDA(0, 1); STG(2, bt + 2, 0);
      TAIL(1, 0); NOP; EBAR();
      // p3
      STG(3, bt + 2, 0);
      TAIL(1, 1); VMC(6); EBAR();
      // p4
      RDA(1, 0); RDB(1, 0); STG(1, bt + 2, 0);
      TAIL(0, 0); NOP; EBAR();
      // p5
      RDB(1, 1); STG(0, bt + 3, 1);
      TAIL(0, 1); NOP; EBAR();
      // p6
      RDA(1, 1); STG(2, bt + 3, 1);
      TAIL(1, 0); NOP; EBAR();
      // p7
      STG(3, bt + 3, 1);
      TAIL(1, 1); VMC(6); EBAR();
    }
    {  // tail iteration: tiles NKT-2 (buf0), NKT-1 (buf1); drain
      int bt = NKT - 2;
      RDA(0, 0); RDB(0, 0); STG(1, bt + 1, 1);
      TAIL(0, 0); NOP; EBAR();
      RDB(0, 1);
      TAIL(0, 1); NOP; EBAR();
      RDA(0, 1);
      TAIL(1, 0); NOP; EBAR();
      TAIL(1, 1); VMC(4); EBAR();
      RDA(1, 0); RDB(1, 0);
      TAIL(0, 0); VMC(2); EBAR();
      RDB(1, 1);
      TAIL(0, 1); VMC(0); EBAR();
      RDA(1, 1);
      TAIL(1, 0); NOP; EBAR();
      TAIL(1, 1); NOP; EBAR();
    }

    if (!g2) {
      // ======== GEMM1 epilogue: hdst = relu(acc + b1) ========
      size_t hrow0 = (size_t)tloc * BM;
#pragma unroll
      for (int nq = 0; nq < 2; ++nq) {
#pragma unroll
        for (int nt = 0; nt < 2; ++nt) {
          int gcol = nb + nq * 128 + wn * 32 + nt * 16 + lrow;
          float bias = b1[e * HID + gcol];
#pragma unroll
          for (int mq = 0; mq < 2; ++mq) {
#pragma unroll
            for (int mt = 0; mt < 4; ++mt) {
#pragma unroll
              for (int j = 0; j < 4; ++j) {
                int grow = mq * 128 + wm * 64 + mt * 16 + quad * 4 + j;
                float v = acc[mq * 4 + mt][nq * 2 + nt][j] + bias;
                hdst[(hrow0 + grow) * HID + gcol] = f2bf(v > 0.f ? v : 0.f);
              }
            }
          }
        }
      }
    } else {
      // ======== GEMM2 epilogue: y[slot] = gate*(acc + b2) ========
      float bias[2][2];
#pragma unroll
      for (int nq = 0; nq < 2; ++nq)
#pragma unroll
        for (int nt = 0; nt < 2; ++nt)
          bias[nq][nt] = b2[e * DIM + nb + nq * 128 + wn * 32 + nt * 16 + lrow];
      if (yslot) {
#pragma unroll
        for (int mq = 0; mq < 2; ++mq) {
#pragma unroll
          for (int mt = 0; mt < 4; ++mt) {
#pragma unroll
            for (int j = 0; j < 4; ++j) {
              int p = row0 + mq * 128 + wm * 64 + mt * 16 + quad * 4 + j;
              float g = pgate[p];
              unsigned short* yr = yslot + (size_t)p * DIM + nb + wn * 32 + lrow;
#pragma unroll
              for (int nq = 0; nq < 2; ++nq)
#pragma unroll
                for (int nt = 0; nt < 2; ++nt)
                  yr[nq * 128 + nt * 16] = f2bf(g * (acc[mq * 4 + mt][nq * 2 + nt][j] + bias[nq][nt]));
            }
          }
        }
      } else {
#pragma unroll
        for (int mq = 0; mq < 2; ++mq) {
#pragma unroll
          for (int mt = 0; mt < 4; ++mt) {
#pragma unroll
            for (int j = 0; j < 4; ++j) {
              int p = row0 + mq * 128 + wm * 64 + mt * 16 + quad * 4 + j;
              float g = pgate[p];
              if (g != 0.f) {
                int tok = ptok[p];
                float* orow = out + (size_t)tok * DIM + nb + wn * 32 + lrow;
#pragma unroll
                for (int nq = 0; nq < 2; ++nq)
#pragma unroll
                  for (int nt = 0; nt < 2; ++nt)
                    atomicAdd(orow + nq * 128 + nt * 16, g * (acc[mq * 4 + mt][nq * 2 + nt][j] + bias[nq][nt]));
              }
            }
          }
        }
      }
    }
  }
}

// out[t][d] = sum_k yslot[sinv[t*4+k]][d]   (yslot is bf16)
__global__ __launch_bounds__(256) void k_gather(const unsigned short* __restrict__ yslot,
                                                const int* __restrict__ sinv,
                                                float* __restrict__ out) {
  int id = blockIdx.x * 256 + threadIdx.x;
  int t = id >> 7, d4 = (id & 127) << 2;
  int4 s = *(const int4*)(sinv + t * 4);
  int sl[4] = {s.x, s.y, s.z, s.w};
  float sum0 = 0.f, sum1 = 0.f, sum2 = 0.f, sum3 = 0.f;
#pragma unroll
  for (int k = 0; k < 4; ++k) {
    ushort4 v = *(const ushort4*)(yslot + (size_t)sl[k] * DIM + d4);
    sum0 += bf2f(v.x); sum1 += bf2f(v.y); sum2 += bf2f(v.z); sum3 += bf2f(v.w);
  }
  float4 r; r.x = sum0; r.y = sum1; r.z = sum2; r.w = sum3;
  *(float4*)(out + (size_t)t * DIM + d4) = r;
}

extern "C" void kernel_launch(void* const* d_in, const int* in_sizes, int n_in,
                              void* d_out, int out_size, void* d_ws, size_t ws_size,
                              hipStream_t stream) {
  const float* x  = (const float*)d_in[0];
  const float* rw = (const float*)d_in[1];
  const float* rb = (const float*)d_in[2];
  const float* w1 = (const float*)d_in[3];
  const float* b1 = (const float*)d_in[4];
  const float* w2 = (const float*)d_in[5];
  const float* b2 = (const float*)d_in[6];
  float* out = (float*)d_out;
  char* ws = (char*)d_ws;

  size_t o_xb    = 0;
  size_t o_w1t   = o_xb    + (size_t)T_TOK * DIM * 2;
  size_t o_w2t   = o_w1t   + (size_t)NE * DIM * HID * 2;
  size_t o_topki = o_w2t   + (size_t)NE * DIM * HID * 2;
  size_t o_topkg = o_topki + (size_t)T_TOK * TOPK * 4;
  size_t o_meta  = o_topkg + (size_t)T_TOK * TOPK * 4;
  size_t o_ptok  = o_meta  + 16384;
  size_t o_pgate = o_ptok  + (size_t)PAIR_CAP * 4;
  size_t o_sinv  = o_pgate + (size_t)PAIR_CAP * 4;
  size_t o_yslot = o_sinv  + (size_t)T_TOK * TOPK * 4;
  size_t o_hb    = o_yslot + (size_t)PAIR_CAP * DIM * 2;   // bf16 yslot

  unsigned short* xb   = (unsigned short*)(ws + o_xb);
  unsigned short* w1t  = (unsigned short*)(ws + o_w1t);
  unsigned short* w2t  = (unsigned short*)(ws + o_w2t);
  int*            tki  = (int*)(ws + o_topki);
  float*          tkg  = (float*)(ws + o_topkg);
  int*            meta = (int*)(ws + o_meta);
  int*            ptok = (int*)(ws + o_ptok);
  float*          pgt  = (float*)(ws + o_pgate);
  int*            sinv = (int*)(ws + o_sinv);

  size_t tile_h = (size_t)BM * HID * 2;   // 1 MB per 256-row tile
  size_t avail = ws_size > o_hb ? ws_size - o_hb : 0;
  long Cd = (long)(avail / (2 * tile_h));
  int use_slot = Cd >= 1;

  k_router<<<T_TOK / 4, 256, 0, stream>>>(x, rw, rb, tki, tkg, xb);
  k_transpose_cast<<<dim3(HID / 32, DIM / 32, NE), dim3(32, 8), 0, stream>>>(w1, w1t, DIM, HID);
  k_transpose_cast<<<dim3(DIM / 32, HID / 32, NE), dim3(32, 8), 0, stream>>>(w2, w2t, HID, DIM);
  k_count<<<NB_CNT, 256, 0, stream>>>(tki, meta);
  k_plan<<<1, 256, 0, stream>>>(meta, ptok, pgt);
  k_scatter<<<NB_CNT, 256, 0, stream>>>(tki, tkg, meta, ptok, pgt, sinv);

  if (use_slot) {
    unsigned short* ysl = (unsigned short*)(ws + o_yslot);
    int C = (int)(Cd > MAX_TILES ? MAX_TILES : Cd);
    int n_chunks = (MAX_TILES + C - 1) / C;
    unsigned short* hb0 = (unsigned short*)(ws + o_hb);
    unsigned short* hb1 = hb0 + (size_t)C * BM * HID;
    for (int i = 0; i <= n_chunks; ++i) {
      unsigned short* dst = (i & 1) ? hb1 : hb0;
      unsigned short* src = (i & 1) ? hb0 : hb1;
      int c1 = (i < n_chunks) ? i : -1;
      int c2 = i - 1;
      k_pipe<<<256, 512, 0, stream>>>(xb, w1t, b1, w2t, b2, ptok, pgt, meta,
                                      meta + QOFF + i, dst, src, ysl, out, c1, c2, C);
    }
    k_gather<<<T_TOK * DIM / 4 / 256, 256, 0, stream>>>(ysl, sinv, out);
  } else {
    // fallback: single hbuf at o_yslot, serial role launches, atomic epilogue
    long Cf = (long)((ws_size - o_yslot) / tile_h);
    int C = (int)(Cf < 1 ? 1 : (Cf > MAX_TILES ? MAX_TILES : Cf));
    int n_chunks = (MAX_TILES + C - 1) / C;
    unsigned short* hb = (unsigned short*)(ws + o_yslot);
    hipMemsetAsync(d_out, 0, (size_t)T_TOK * DIM * 4, stream);
    for (int i = 0; i < n_chunks; ++i) {
      k_pipe<<<256, 512, 0, stream>>>(xb, w1t, b1, w2t, b2, ptok, pgt, meta,
                                      meta + QOFF + 2 * i, hb, hb, nullptr, out, i, -1, C);
      k_pipe<<<256, 512, 0, stream>>>(xb, w1t, b1, w2t, b2, ptok, pgt, meta,
                                      meta + QOFF + 2 * i + 1, hb, hb, nullptr, out, -1, i, C);
    }
  }
}

// Round 5
// 618.689 us; speedup vs baseline: 1.2084x; 1.0931x over previous
//
#include <hip/hip_runtime.h>
#include <stdint.h>

#define T_TOK 16384
#define DIM 512
#define HID 2048
#define NE 16
#define TOPK 4
#define BM 256
#define BN 256
#define BKT 64
#define PAIR_CAP 69632      // 65536 + 16*256 padding
#define MAX_TILES 272       // PAIR_CAP / BM
#define NB_CNT 64
#define QOFF 2080           // meta[] index of per-launch queue counters

typedef short s8v __attribute__((ext_vector_type(8)));
typedef float f4v __attribute__((ext_vector_type(4)));
typedef unsigned int u4v __attribute__((ext_vector_type(4)));

__device__ __forceinline__ unsigned short f2bf(float f) {
  unsigned int u = __builtin_bit_cast(unsigned int, f);
  u = (u + 0x7fffu + ((u >> 16) & 1u)) >> 16;
  return (unsigned short)u;
}
__device__ __forceinline__ float bf2f(unsigned short h) {
  return __builtin_bit_cast(float, (unsigned int)h << 16);
}

// async global->LDS, 16B per lane. LDS dest is wave-uniform base + lane*16.
__device__ __forceinline__ void gload16(const void* g, void* l) {
  __builtin_amdgcn_global_load_lds(
      (const __attribute__((address_space(1))) unsigned int*)(uintptr_t)g,
      (__attribute__((address_space(3))) unsigned int*)(uintptr_t)l,
      16, 0, 0);
}

// src [z][R][C] fp32 -> dst [z][C][R] bf16
__global__ __launch_bounds__(256) void k_transpose_cast(const float* __restrict__ src,
                                                        unsigned short* __restrict__ dst,
                                                        int R, int C) {
  __shared__ float tile[32][33];
  size_t zo = (size_t)blockIdx.z * R * C;
  src += zo; dst += zo;
  int c0 = blockIdx.x * 32, r0 = blockIdx.y * 32;
  int tx = threadIdx.x, ty = threadIdx.y;
#pragma unroll
  for (int i = 0; i < 4; ++i)
    tile[ty + 8 * i][tx] = src[(size_t)(r0 + ty + 8 * i) * C + c0 + tx];
  __syncthreads();
#pragma unroll
  for (int i = 0; i < 4; ++i)
    dst[(size_t)(c0 + ty + 8 * i) * R + r0 + tx] = f2bf(tile[tx][ty + 8 * i]);
}

// ---------------- routing (+ fused x->bf16 cast) ----------------
__global__ __launch_bounds__(256) void k_router(const float* __restrict__ x,
                                                const float* __restrict__ rw,
                                                const float* __restrict__ rb,
                                                int* __restrict__ topki,
                                                float* __restrict__ topkg,
                                                unsigned short* __restrict__ xb) {
  int wv = threadIdx.x >> 6, lane = threadIdx.x & 63;
  int t = blockIdx.x * 4 + wv;
  const float* xr = x + (size_t)t * DIM;
  unsigned short* xbr = xb + (size_t)t * DIM;
  double acc[NE];
#pragma unroll
  for (int e = 0; e < NE; ++e) acc[e] = 0.0;
  for (int it = 0; it < DIM / 64; ++it) {
    float xv = xr[it * 64 + lane];
    xbr[it * 64 + lane] = f2bf(xv);
    const float* r = rw + (size_t)(it * 64 + lane) * NE;
#pragma unroll
    for (int e = 0; e < NE; ++e) acc[e] += (double)xv * (double)r[e];
  }
#pragma unroll
  for (int off = 32; off >= 1; off >>= 1) {
#pragma unroll
    for (int e = 0; e < NE; ++e) acc[e] += __shfl_xor(acc[e], off, 64);
  }
  if (lane == 0) {
    float v[NE];
#pragma unroll
    for (int e = 0; e < NE; ++e) v[e] = (float)acc[e] + rb[e];
    int idx[TOPK]; float val[TOPK];
#pragma unroll
    for (int k = 0; k < TOPK; ++k) {
      float best = -1e30f; int bi = 0;
#pragma unroll
      for (int e = 0; e < NE; ++e)
        if (v[e] > best) { best = v[e]; bi = e; }
      idx[k] = bi; val[k] = best; v[bi] = -1e30f;
    }
    float m = val[0], s = 0.f, g[TOPK];
#pragma unroll
    for (int k = 0; k < TOPK; ++k) { g[k] = __expf(val[k] - m); s += g[k]; }
    float inv = 1.f / s;
#pragma unroll
    for (int k = 0; k < TOPK; ++k) {
      topki[t * TOPK + k] = idx[k];
      topkg[t * TOPK + k] = g[k] * inv;
    }
  }
}

// meta layout (ints): [0]=tiles_total, [1..17]=padded offsets po[0..16],
// [32..1055]=blockbase[64][16], [1056..2079]=hist[64][16],
// [2080..3103]=work-queue counters (one per k_pipe launch)
__global__ __launch_bounds__(256) void k_count(const int* __restrict__ topki,
                                               int* __restrict__ meta) {
  __shared__ int lcnt[NE];
  int tid = threadIdx.x;
  if (tid < NE) lcnt[tid] = 0;
  __syncthreads();
  int base = blockIdx.x * 1024 + tid * 4;
#pragma unroll
  for (int j = 0; j < 4; ++j) atomicAdd(&lcnt[topki[base + j]], 1);
  __syncthreads();
  if (tid < NE) meta[1056 + blockIdx.x * NE + tid] = lcnt[tid];
}

__global__ __launch_bounds__(256) void k_plan(int* __restrict__ meta,
                                              int* __restrict__ ptok,
                                              float* __restrict__ pgate) {
  __shared__ int cnt_s[NE], po_s[NE + 1];
  int tid = threadIdx.x;
  for (int i = tid; i < 1024; i += 256) meta[QOFF + i] = 0;
  if (tid < NE) {
    int s = 0;
    for (int b = 0; b < NB_CNT; ++b) s += meta[1056 + b * NE + tid];
    cnt_s[tid] = s;
  }
  __syncthreads();
  if (tid == 0) {
    int off = 0;
    for (int e = 0; e < NE; ++e) {
      po_s[e] = off;
      meta[1 + e] = off;
      off += ((cnt_s[e] + BM - 1) / BM) * BM;
    }
    po_s[NE] = off;
    meta[1 + NE] = off;
    meta[0] = off / BM;
  }
  __syncthreads();
  if (tid < NE) {
    int run = po_s[tid];
    for (int b = 0; b < NB_CNT; ++b) {
      meta[32 + b * NE + tid] = run;
      run += meta[1056 + b * NE + tid];
    }
  }
  for (int e = 0; e < NE; ++e) {
    int start = po_s[e] + cnt_s[e], end = po_s[e + 1];
    for (int i = start + tid; i < end; i += 256) { ptok[i] = 0; pgate[i] = 0.f; }
  }
}

__global__ __launch_bounds__(256) void k_scatter(const int* __restrict__ topki,
                                                 const float* __restrict__ topkg,
                                                 const int* __restrict__ meta,
                                                 int* __restrict__ ptok,
                                                 float* __restrict__ pgate,
                                                 int* __restrict__ sinv) {
  __shared__ int lcnt[NE];
  int tid = threadIdx.x;
  if (tid < NE) lcnt[tid] = 0;
  __syncthreads();
  int base = blockIdx.x * 1024 + tid * 4;
#pragma unroll
  for (int j = 0; j < 4; ++j) {
    int i = base + j;
    int e = topki[i];
    int r = atomicAdd(&lcnt[e], 1);
    int slot = meta[32 + blockIdx.x * NE + e] + r;
    ptok[slot] = i >> 2;
    pgate[slot] = topkg[i];
    sinv[i] = slot;
  }
}

// ---------------- persistent work-queue 256x256 GEMM, 1-barrier phases ----------------
// Grid = 256 blocks (1/CU, 8 waves). Queue: GEMM2 items first (32 K-tiles each),
// then GEMM1 items (8 K-tiles) — LPT ordering keeps the drain tail <= 8 K-tiles.
// Per phase: {ds_reads | STG | setprio(1) MFMA setprio(0) | [vmcnt(N)] | s_barrier}.
// No leading barrier / no lgkmcnt(0): compiler emits counted lgkmcnt before each
// consuming MFMA, so trailing ds_reads drain UNDER the MFMA cluster, and waves skew
// within a phase (early waves' MFMA overlaps later waves' LDS drain).
// Hazard audit (1 barrier suffices): every staged region has >=1 s_barrier between
// the last fragment read (completes before that wave's consuming MFMA issues, which
// is before its s_barrier) and the overwriting STG (issued after the barrier).
// Read map per K-tile: p0: A1+B1+B2 frags (16 ds_read_b128), p2: A2 (8). bfr holds
// both nq halves; af is overwritten by A2 after MMQ(0,1) consumed A1.
// vmcnt ledger (load pairs, FIFO): prologue 7 pairs, VMC(4)=tile0 landed; steady
// VMC(6)@p3 -> buf-next complete, VMC(6)@p7 -> buf-next complete; tail 4/2/0 drain.

#define EBAR() asm volatile("s_barrier" ::: "memory")
#define SP1() __builtin_amdgcn_s_setprio(1)
#define SP0() __builtin_amdgcn_s_setprio(0)
#define VMC(n) asm volatile("s_waitcnt vmcnt(" #n ")" ::: "memory")
#define NOP ((void)0)

// stage half-tile region: rg 0=A1,1=A2,2=B1,3=B2 of K-tile kt into buffer c
#define STG(rg, kt, c) do {                                                            \
    int _k = (kt) * BKT;                                                               \
    if ((rg) < 2) {                                                                    \
      gload16(aP[rg][0] + _k, (char*)&Al[c][0] + (rg) * 16384 + w * 1024);             \
      gload16(aP[rg][1] + _k, (char*)&Al[c][0] + (rg) * 16384 + 8192 + w * 1024);      \
    } else {                                                                           \
      gload16(bP[(rg) - 2][0] + _k, (char*)&Bl[c][0] + ((rg) - 2) * 16384 + w * 1024); \
      gload16(bP[(rg) - 2][1] + _k, (char*)&Bl[c][0] + ((rg) - 2) * 16384 + 8192 + w * 1024); \
    }                                                                                  \
  } while (0)

#define RDA(c, mq) do {                                                                \
    _Pragma("unroll")                                                                  \
    for (int mt = 0; mt < 4; ++mt) {                                                   \
      af[mt][0] = __builtin_bit_cast(s8v, *(const u4v*)&Al[c][(mq) * 8192 + aoff + mt * 1024 + cs0]); \
      af[mt][1] = __builtin_bit_cast(s8v, *(const u4v*)&Al[c][(mq) * 8192 + aoff + mt * 1024 + cs1]); \
    }                                                                                  \
  } while (0)

#define RDB(c, nq) do {                                                                \
    _Pragma("unroll")                                                                  \
    for (int nt = 0; nt < 2; ++nt) {                                                   \
      bfr[nq][nt][0] = __builtin_bit_cast(s8v, *(const u4v*)&Bl[c][(nq) * 8192 + boff + nt * 1024 + cs0]); \
      bfr[nq][nt][1] = __builtin_bit_cast(s8v, *(const u4v*)&Bl[c][(nq) * 8192 + boff + nt * 1024 + cs1]); \
    }                                                                                  \
  } while (0)

#define MMQ(mq, nq) do {                                                               \
    _Pragma("unroll")                                                                  \
    for (int mt = 0; mt < 4; ++mt) {                                                   \
      _Pragma("unroll")                                                                \
      for (int nt = 0; nt < 2; ++nt) {                                                 \
        acc[(mq) * 4 + mt][(nq) * 2 + nt] = __builtin_amdgcn_mfma_f32_16x16x32_bf16(   \
            af[mt][0], bfr[nq][nt][0], acc[(mq) * 4 + mt][(nq) * 2 + nt], 0, 0, 0);    \
        acc[(mq) * 4 + mt][(nq) * 2 + nt] = __builtin_amdgcn_mfma_f32_16x16x32_bf16(   \
            af[mt][1], bfr[nq][nt][1], acc[(mq) * 4 + mt][(nq) * 2 + nt], 0, 0, 0);    \
      }                                                                                \
    }                                                                                  \
  } while (0)

#define FIRE(mq, nq) do { SP1(); MMQ(mq, nq); SP0(); } while (0)

__global__ __launch_bounds__(512, 2) void k_pipe(const unsigned short* xb,
                                                 const unsigned short* w1t,
                                                 const float* b1,
                                                 const unsigned short* w2t,
                                                 const float* b2,
                                                 const int* ptok,
                                                 const float* pgate,
                                                 const int* meta,
                                                 int* qctr,
                                                 unsigned short* hdst,
                                                 const unsigned short* hsrc,
                                                 unsigned short* yslot,
                                                 float* out,
                                                 int c1, int c2, int C) {
  __shared__ __align__(16) unsigned short Al[2][BM * BKT];   // 2 x 32 KB
  __shared__ __align__(16) unsigned short Bl[2][BN * BKT];   // 2 x 32 KB
  __shared__ int sh_item;
  int tid = threadIdx.x;
  int lane = tid & 63, w = tid >> 6;       // 8 waves
  int wm = w >> 2, wn = w & 3;             // 2 x 4 wave grid within a quadrant
  int lrow = lane & 15, quad = lane >> 4;
  int r7 = lrow & 7;
  int sub = lane >> 3, lg = (lane & 7) ^ sub;

  int aoff = (wm * 64 + lrow) * BKT;   // row base within a 128-row A region
  int boff = (wn * 32 + lrow) * BKT;   // row base within a 128-row B region
  int cs0 = (quad ^ r7) * 8;
  int cs1 = ((4 + quad) ^ r7) * 8;

  int T = meta[0];
  int t2 = 0, t1 = 0;
  if (c2 >= 0) { t2 = T - c2 * C; t2 = t2 < 0 ? 0 : (t2 > C ? C : t2); }
  if (c1 >= 0) { t1 = T - c1 * C; t1 = t1 < 0 ? 0 : (t1 > C ? C : t1); }
  int n2 = 2 * t2, nit = n2 + 8 * t1;

  for (;;) {
    if (tid == 0) sh_item = atomicAdd(qctr, 1);
    __syncthreads();
    int it = sh_item;
    if (it >= nit) break;

    bool g2 = it < n2;
    int tloc, nb, tile;
    if (g2) { tloc = it >> 1; nb = (it & 1) * BN; tile = c2 * C + tloc; }
    else { int j = it - n2; tloc = j >> 3; nb = (j & 7) * BN; tile = c1 * C + tloc; }
    int row0 = tile * BM;
    int e = 0;
#pragma unroll
    for (int i2 = 1; i2 < NE; ++i2)
      if (row0 >= meta[1 + i2]) e = i2;

    const unsigned short* aP[2][2];
    const unsigned short* bP[2][2];
    int NKT;
    if (!g2) {
      NKT = DIM / BKT;   // 8
#pragma unroll
      for (int h = 0; h < 2; ++h)
#pragma unroll
        for (int t = 0; t < 2; ++t) {
          int r = h * 128 + t * 64 + w * 8 + sub;
          aP[h][t] = xb + (size_t)ptok[row0 + r] * DIM + lg * 8;
          bP[h][t] = w1t + ((size_t)e * HID + nb + r) * DIM + lg * 8;
        }
    } else {
      NKT = HID / BKT;   // 32
#pragma unroll
      for (int h = 0; h < 2; ++h)
#pragma unroll
        for (int t = 0; t < 2; ++t) {
          int r = h * 128 + t * 64 + w * 8 + sub;
          aP[h][t] = hsrc + ((size_t)tloc * BM + r) * HID + lg * 8;
          bP[h][t] = w2t + ((size_t)e * DIM + nb + r) * HID + lg * 8;
        }
    }

    f4v acc[8][4] = {};
    s8v af[4][2];
    s8v bfr[2][2][2];

    // prologue: buf0 <- tile0 (A1,B1,B2,A2); buf1 <- tile1 (A1,B1,B2)
    STG(0, 0, 0); STG(2, 0, 0); STG(3, 0, 0); STG(1, 0, 0);
    STG(0, 1, 1); STG(2, 1, 1); STG(3, 1, 1);
    VMC(4);
    EBAR();

    int NI = NKT >> 1;
    for (int i = 0; i < NI - 1; ++i) {
      int bt = 2 * i;
      // p0: read A1,B1,B2 frags of buf0; stage A2(bt+1)->buf1
      RDA(0, 0); RDB(0, 0); RDB(0, 1); STG(1, bt + 1, 1);
      FIRE(0, 0); EBAR();
      // p1: stage A1(bt+2)->buf0
      STG(0, bt + 2, 0);
      FIRE(0, 1); EBAR();
      // p2: read A2 frags; stage B1(bt+2)->buf0
      RDA(0, 1); STG(2, bt + 2, 0);
      FIRE(1, 0); EBAR();
      // p3: stage B2(bt+2)->buf0; guard: tile bt+1 landed
      STG(3, bt + 2, 0);
      FIRE(1, 1); VMC(6); EBAR();
      // p4: read buf1 frags; stage A2(bt+2)->buf0
      RDA(1, 0); RDB(1, 0); RDB(1, 1); STG(1, bt + 2, 0);
      FIRE(0, 0); EBAR();
      // p5: stage A1(bt+3)->buf1
      STG(0, bt + 3, 1);
      FIRE(0, 1); EBAR();
      // p6: read A2 of buf1; stage B1(bt+3)->buf1
      RDA(1, 1); STG(2, bt + 3, 1);
      FIRE(1, 0); EBAR();
      // p7: stage B2(bt+3)->buf1; guard: tile bt+2 landed
      STG(3, bt + 3, 1);
      FIRE(1, 1); VMC(6); EBAR();
    }
    {  // tail iteration: tiles NKT-2 (buf0), NKT-1 (buf1); drain 4/2/0
      int bt = NKT - 2;
      RDA(0, 0); RDB(0, 0); RDB(0, 1); STG(1, bt + 1, 1);
      FIRE(0, 0); EBAR();
      FIRE(0, 1); EBAR();
      RDA(0, 1);
      FIRE(1, 0); EBAR();
      FIRE(1, 1); VMC(4); EBAR();
      RDA(1, 0); RDB(1, 0);
      FIRE(0, 0); VMC(2); EBAR();
      RDB(1, 1);
      FIRE(0, 1); VMC(0); EBAR();
      RDA(1, 1);
      FIRE(1, 0); EBAR();
      FIRE(1, 1); EBAR();
    }

    if (!g2) {
      // ======== GEMM1 epilogue: hdst = relu(acc + b1), row-outer store order ========
      size_t hrow0 = (size_t)tloc * BM;
      float bias[2][2];
#pragma unroll
      for (int nq = 0; nq < 2; ++nq)
#pragma unroll
        for (int nt = 0; nt < 2; ++nt)
          bias[nq][nt] = b1[e * HID + nb + nq * 128 + wn * 32 + nt * 16 + lrow];
#pragma unroll
      for (int mq = 0; mq < 2; ++mq) {
#pragma unroll
        for (int mt = 0; mt < 4; ++mt) {
#pragma unroll
          for (int j = 0; j < 4; ++j) {
            int grow = mq * 128 + wm * 64 + mt * 16 + quad * 4 + j;
            unsigned short* hr = hdst + (hrow0 + grow) * HID + nb + wn * 32 + lrow;
#pragma unroll
            for (int nq = 0; nq < 2; ++nq)
#pragma unroll
              for (int nt = 0; nt < 2; ++nt) {
                float v = acc[mq * 4 + mt][nq * 2 + nt][j] + bias[nq][nt];
                hr[nq * 128 + nt * 16] = f2bf(v > 0.f ? v : 0.f);
              }
          }
        }
      }
    } else {
      // ======== GEMM2 epilogue: y[slot] = gate*(acc + b2) ========
      float bias[2][2];
#pragma unroll
      for (int nq = 0; nq < 2; ++nq)
#pragma unroll
        for (int nt = 0; nt < 2; ++nt)
          bias[nq][nt] = b2[e * DIM + nb + nq * 128 + wn * 32 + nt * 16 + lrow];
      if (yslot) {
#pragma unroll
        for (int mq = 0; mq < 2; ++mq) {
#pragma unroll
          for (int mt = 0; mt < 4; ++mt) {
#pragma unroll
            for (int j = 0; j < 4; ++j) {
              int p = row0 + mq * 128 + wm * 64 + mt * 16 + quad * 4 + j;
              float g = pgate[p];
              unsigned short* yr = yslot + (size_t)p * DIM + nb + wn * 32 + lrow;
#pragma unroll
              for (int nq = 0; nq < 2; ++nq)
#pragma unroll
                for (int nt = 0; nt < 2; ++nt)
                  yr[nq * 128 + nt * 16] = f2bf(g * (acc[mq * 4 + mt][nq * 2 + nt][j] + bias[nq][nt]));
            }
          }
        }
      } else {
#pragma unroll
        for (int mq = 0; mq < 2; ++mq) {
#pragma unroll
          for (int mt = 0; mt < 4; ++mt) {
#pragma unroll
            for (int j = 0; j < 4; ++j) {
              int p = row0 + mq * 128 + wm * 64 + mt * 16 + quad * 4 + j;
              float g = pgate[p];
              if (g != 0.f) {
                int tok = ptok[p];
                float* orow = out + (size_t)tok * DIM + nb + wn * 32 + lrow;
#pragma unroll
                for (int nq = 0; nq < 2; ++nq)
#pragma unroll
                  for (int nt = 0; nt < 2; ++nt)
                    atomicAdd(orow + nq * 128 + nt * 16, g * (acc[mq * 4 + mt][nq * 2 + nt][j] + bias[nq][nt]));
              }
            }
          }
        }
      }
    }
  }
}

// out[t][d] = sum_k yslot[sinv[t*4+k]][d]   (yslot is bf16)
__global__ __launch_bounds__(256) void k_gather(const unsigned short* __restrict__ yslot,
                                                const int* __restrict__ sinv,
                                                float* __restrict__ out) {
  int id = blockIdx.x * 256 + threadIdx.x;
  int t = id >> 7, d4 = (id & 127) << 2;
  int4 s = *(const int4*)(sinv + t * 4);
  int sl[4] = {s.x, s.y, s.z, s.w};
  float sum0 = 0.f, sum1 = 0.f, sum2 = 0.f, sum3 = 0.f;
#pragma unroll
  for (int k = 0; k < 4; ++k) {
    ushort4 v = *(const ushort4*)(yslot + (size_t)sl[k] * DIM + d4);
    sum0 += bf2f(v.x); sum1 += bf2f(v.y); sum2 += bf2f(v.z); sum3 += bf2f(v.w);
  }
  float4 r; r.x = sum0; r.y = sum1; r.z = sum2; r.w = sum3;
  *(float4*)(out + (size_t)t * DIM + d4) = r;
}

extern "C" void kernel_launch(void* const* d_in, const int* in_sizes, int n_in,
                              void* d_out, int out_size, void* d_ws, size_t ws_size,
                              hipStream_t stream) {
  const float* x  = (const float*)d_in[0];
  const float* rw = (const float*)d_in[1];
  const float* rb = (const float*)d_in[2];
  const float* w1 = (const float*)d_in[3];
  const float* b1 = (const float*)d_in[4];
  const float* w2 = (const float*)d_in[5];
  const float* b2 = (const float*)d_in[6];
  float* out = (float*)d_out;
  char* ws = (char*)d_ws;

  size_t o_xb    = 0;
  size_t o_w1t   = o_xb    + (size_t)T_TOK * DIM * 2;
  size_t o_w2t   = o_w1t   + (size_t)NE * DIM * HID * 2;
  size_t o_topki = o_w2t   + (size_t)NE * DIM * HID * 2;
  size_t o_topkg = o_topki + (size_t)T_TOK * TOPK * 4;
  size_t o_meta  = o_topkg + (size_t)T_TOK * TOPK * 4;
  size_t o_ptok  = o_meta  + 16384;
  size_t o_pgate = o_ptok  + (size_t)PAIR_CAP * 4;
  size_t o_sinv  = o_pgate + (size_t)PAIR_CAP * 4;
  size_t o_yslot = o_sinv  + (size_t)T_TOK * TOPK * 4;
  size_t o_hb    = o_yslot + (size_t)PAIR_CAP * DIM * 2;   // bf16 yslot

  unsigned short* xb   = (unsigned short*)(ws + o_xb);
  unsigned short* w1t  = (unsigned short*)(ws + o_w1t);
  unsigned short* w2t  = (unsigned short*)(ws + o_w2t);
  int*            tki  = (int*)(ws + o_topki);
  float*          tkg  = (float*)(ws + o_topkg);
  int*            meta = (int*)(ws + o_meta);
  int*            ptok = (int*)(ws + o_ptok);
  float*          pgt  = (float*)(ws + o_pgate);
  int*            sinv = (int*)(ws + o_sinv);

  size_t tile_h = (size_t)BM * HID * 2;   // 1 MB per 256-row tile
  size_t avail = ws_size > o_hb ? ws_size - o_hb : 0;
  long Cd = (long)(avail / (2 * tile_h));
  int use_slot = Cd >= 1;

  k_router<<<T_TOK / 4, 256, 0, stream>>>(x, rw, rb, tki, tkg, xb);
  k_transpose_cast<<<dim3(HID / 32, DIM / 32, NE), dim3(32, 8), 0, stream>>>(w1, w1t, DIM, HID);
  k_transpose_cast<<<dim3(DIM / 32, HID / 32, NE), dim3(32, 8), 0, stream>>>(w2, w2t, HID, DIM);
  k_count<<<NB_CNT, 256, 0, stream>>>(tki, meta);
  k_plan<<<1, 256, 0, stream>>>(meta, ptok, pgt);
  k_scatter<<<NB_CNT, 256, 0, stream>>>(tki, tkg, meta, ptok, pgt, sinv);

  if (use_slot) {
    unsigned short* ysl = (unsigned short*)(ws + o_yslot);
    int C = (int)(Cd > MAX_TILES ? MAX_TILES : Cd);
    int n_chunks = (MAX_TILES + C - 1) / C;
    unsigned short* hb0 = (unsigned short*)(ws + o_hb);
    unsigned short* hb1 = hb0 + (size_t)C * BM * HID;
    for (int i = 0; i <= n_chunks; ++i) {
      unsigned short* dst = (i & 1) ? hb1 : hb0;
      unsigned short* src = (i & 1) ? hb0 : hb1;
      int c1 = (i < n_chunks) ? i : -1;
      int c2 = i - 1;
      k_pipe<<<256, 512, 0, stream>>>(xb, w1t, b1, w2t, b2, ptok, pgt, meta,
                                      meta + QOFF + i, dst, src, ysl, out, c1, c2, C);
    }
    k_gather<<<T_TOK * DIM / 4 / 256, 256, 0, stream>>>(ysl, sinv, out);
  } else {
    // fallback: single hbuf at o_yslot, serial role launches, atomic epilogue
    long Cf = (long)((ws_size - o_yslot) / tile_h);
    int C = (int)(Cf < 1 ? 1 : (Cf > MAX_TILES ? MAX_TILES : Cf));
    int n_chunks = (MAX_TILES + C - 1) / C;
    unsigned short* hb = (unsigned short*)(ws + o_yslot);
    hipMemsetAsync(d_out, 0, (size_t)T_TOK * DIM * 4, stream);
    for (int i = 0; i < n_chunks; ++i) {
      k_pipe<<<256, 512, 0, stream>>>(xb, w1t, b1, w2t, b2, ptok, pgt, meta,
                                      meta + QOFF + 2 * i, hb, hb, nullptr, out, i, -1, C);
      k_pipe<<<256, 512, 0, stream>>>(xb, w1t, b1, w2t, b2, ptok, pgt, meta,
                                      meta + QOFF + 2 * i + 1, hb, hb, nullptr, out, -1, i, C);
    }
  }
}